// Round 9
// baseline (335.077 us; speedup 1.0000x reference)
//
#include <hip/hip_runtime.h>
#include <hip/hip_bf16.h>

// ---------------------------------------------------------------------------
// EdgeConvNet — Round 9: exact-fill persistent launch (1536 blocks = 6/CU).
//
// R8 counters: VGPR=80 -> 6 waves/SIMD capacity (75%), but 2048 persistent
// blocks > 1536 resident slots -> 512 blocks ran as a sparse second round;
// measured occupancy 28%. R9 launches exactly the resident capacity and pins
// VGPR via __launch_bounds__(256,6). Inner loop unchanged from R8 (proven):
//   - f16 feature pre-pass into d_ws (halves gather bytes, L2-friendly)
//   - per 2-edge tile: packed-f16 conv -> 16x16x32 f16 MFMA (swapped
//     operands) -> in-lane fc2 partial; depth-2 prefetch crossing groups
//   - batched epilogue: 8 tiles' shuffle chains interleaved pass-wise
// ---------------------------------------------------------------------------

typedef _Float16 f16x8 __attribute__((ext_vector_type(8)));
typedef _Float16 f16x4 __attribute__((ext_vector_type(4)));
typedef _Float16 f16x2 __attribute__((ext_vector_type(2)));
typedef short    bf16x8 __attribute__((ext_vector_type(8)));
typedef float    f32x4  __attribute__((ext_vector_type(4)));
typedef float    f32x2  __attribute__((ext_vector_type(2)));

union U8 { f16x8 v; f16x2 p[4]; };

static __device__ __forceinline__ short f2bf(float f) {
    union { __hip_bfloat16 h; short s; } u;
    u.h = __float2bfloat16(f);
    return u.s;
}

// ---------------------------- pre-pass ------------------------------------
__global__ __launch_bounds__(256) void feat_to_f16(const float* __restrict__ in,
                                                   _Float16* __restrict__ out,
                                                   int n4) {
    int i = blockIdx.x * blockDim.x + threadIdx.x;
    const int stride = gridDim.x * blockDim.x;
    for (; i < n4; i += stride) {
        const f32x4 v = ((const f32x4*)in)[i];
        ((f16x4*)out)[i] = __builtin_convertvector(v, f16x4);
    }
}

// ---------------- main (persistent, exact-fill, batched epilogue) ----------
__global__ __launch_bounds__(256, 6) void edgeconv_f16_xf(
    const _Float16* __restrict__ feat16,     // (50000, 64) f16 (in d_ws)
    const int*      __restrict__ edge_index, // (2, E) int32
    const float* __restrict__ conv_w, const float* __restrict__ conv_b,
    const float* __restrict__ w1,     const float* __restrict__ b1,
    const float* __restrict__ w2,     const float* __restrict__ b2,
    const float* __restrict__ w3,     const float* __restrict__ b3,
    float* __restrict__ out, int nEdges)
{
    const int tid = threadIdx.x;
    const int l   = tid & 63;
    const int wid = tid >> 6;
    const int grp = l >> 4;        // k-slice group 0..3
    const int n   = l & 15;        // A row = g ; B col = edge·ch
    const int ch  = l & 7;
    const int el  = (l >> 3) & 1;

    // A fragments: w1[g=n][f], f = grp*8+i (+32 for 2nd MFMA), in f16
    const float* w1r = w1 + n * 64 + grp * 8;
    f16x8 aw0, aw1;
    #pragma unroll
    for (int i = 0; i < 8; ++i) {
        aw0[i] = (_Float16)w1r[i];
        aw1[i] = (_Float16)w1r[32 + i];
    }

    // conv params as packed-f16 splats
    const _Float16 cah = (_Float16)conv_w[2 * ch];
    const _Float16 cch = (_Float16)conv_w[2 * ch + 1];
    const _Float16 cbh = (_Float16)conv_b[ch];
    const f16x2 vca = {cah, cah}, vcc = {cch, cch}, vcb = {cbh, cbh};
    const f16x2 vzero = {(_Float16)0.f, (_Float16)0.f};

    float b1r[4], w2r[4];
    #pragma unroll
    for (int r = 0; r < 4; ++r) {
        b1r[r] = b1[grp * 4 + r];
        w2r[r] = w2[grp * 4 + r];
    }
    const float w3v = w3[ch];
    const float b2v = b2[0];
    const float b3v = b3[0];

    const int nGroups    = (nEdges + 15) >> 4;   // 16-edge groups (8 tiles)
    const int totalWaves = gridDim.x * 4;
    int g = blockIdx.x * 4 + wid;
    if (g >= nGroups) return;

#define LOADT(VS, VD, T, SLo, SHi, DLo, DHi) do { \
    const int sn_ = __shfl((VS), 2 * (T) + el); \
    const int dn_ = __shfl((VD), 2 * (T) + el); \
    const _Float16* ps_ = feat16 + (size_t)sn_ * 64 + grp * 8; \
    const _Float16* pd_ = feat16 + (size_t)dn_ * 64 + grp * 8; \
    SLo = *(const f16x8*)(ps_);  SHi = *(const f16x8*)(ps_ + 32); \
    DLo = *(const f16x8*)(pd_);  DHi = *(const f16x8*)(pd_ + 32); \
} while (0)

    // prologue: first group's indices; prefetch its tiles 0,1
    int ce = min(g * 16 + n, nEdges - 1);
    int vs = edge_index[ce];
    int vd = edge_index[nEdges + ce];

    f16x8 sL[2], sH[2], dL[2], dH[2];
    LOADT(vs, vd, 0, sL[0], sH[0], dL[0], dH[0]);
    LOADT(vs, vd, 1, sL[1], sH[1], dL[1], dH[1]);

    while (true) {
        const int gn    = g + totalWaves;
        const bool more = (gn < nGroups);
        int vsn = 0, vdn = 0;
        if (more) {                               // preload next group's indices
            const int cen = min(gn * 16 + n, nEdges - 1);
            vsn = edge_index[cen];
            vdn = edge_index[nEdges + cen];
        }

        // ---------------- phase 1: conv + MFMA + in-lane fc2 ----------------
        float zp[8];
        #pragma unroll
        for (int t = 0; t < 8; ++t) {
            const int b = t & 1;

            U8 s0_, s1_, d0_, d1_, c0, c1;
            s0_.v = sL[b]; s1_.v = sH[b];
            d0_.v = dL[b]; d1_.v = dH[b];
            #pragma unroll
            for (int p = 0; p < 4; ++p) {
                f16x2 tL = __builtin_elementwise_fma(vca, s0_.p[p],
                            __builtin_elementwise_fma(vcc, d0_.p[p], vcb));
                c0.p[p] = __builtin_elementwise_max(tL, vzero);
                f16x2 tH = __builtin_elementwise_fma(vca, s1_.p[p],
                            __builtin_elementwise_fma(vcc, d1_.p[p], vcb));
                c1.p[p] = __builtin_elementwise_max(tH, vzero);
            }

            // prefetch into buffer just consumed (crosses group boundary)
            if (t < 6)      LOADT(vs,  vd,  t + 2, sL[b], sH[b], dL[b], dH[b]);
            else if (more)  LOADT(vsn, vdn, t - 6, sL[b], sH[b], dL[b], dH[b]);

            f32x4 acc = {0.f, 0.f, 0.f, 0.f};
            acc = __builtin_amdgcn_mfma_f32_16x16x32_f16(aw0, c0.v, acc, 0, 0, 0);
            acc = __builtin_amdgcn_mfma_f32_16x16x32_f16(aw1, c1.v, acc, 0, 0, 0);

            float z_ = 0.f;
            #pragma unroll
            for (int r = 0; r < 4; ++r) {
                const float h1 = fmaxf(acc[r] + b1r[r], 0.f);
                z_ = fmaf(h1, w2r[r], z_);
            }
            zp[t] = z_;
        }

        // ---------------- phase 2: batched shuffle reduces ------------------
        #pragma unroll
        for (int t = 0; t < 8; ++t) zp[t] += __shfl_xor(zp[t], 16);
        #pragma unroll
        for (int t = 0; t < 8; ++t) zp[t] += __shfl_xor(zp[t], 32);
        #pragma unroll
        for (int t = 0; t < 8; ++t) {
            const float h2 = fmaxf(zp[t] + b2v, 0.f);
            zp[t] = h2 * w3v;
        }
        #pragma unroll
        for (int t = 0; t < 8; ++t) zp[t] += __shfl_xor(zp[t], 1);
        #pragma unroll
        for (int t = 0; t < 8; ++t) zp[t] += __shfl_xor(zp[t], 2);
        #pragma unroll
        for (int t = 0; t < 8; ++t) zp[t] += __shfl_xor(zp[t], 4);
        #pragma unroll
        for (int t = 0; t < 8; ++t) {
            const float z  = zp[t] + b3v;
            const float sg = 1.0f / (1.0f + __expf(-z));
            if ((l & 55) == 0) {                  // lanes 0 (el=0), 8 (el=1)
                const int e = g * 16 + 2 * t + (l >> 3);
                if (e < nEdges) out[e] = sg;
            }
        }

        if (!more) break;
        g = gn; vs = vsn; vd = vdn;
    }
#undef LOADT
}

// ------------------- fallback: round-4 bf16 kernel (proven) ----------------
__global__ __launch_bounds__(256) void edgeconv_mfma2(
    const float* __restrict__ features, const int* __restrict__ edge_index,
    const float* __restrict__ conv_w, const float* __restrict__ conv_b,
    const float* __restrict__ w1, const float* __restrict__ b1,
    const float* __restrict__ w2, const float* __restrict__ b2,
    const float* __restrict__ w3, const float* __restrict__ b3,
    float* __restrict__ out, int nEdges)
{
    const int tid = threadIdx.x;
    const int l   = tid & 63;
    const int wid = tid >> 6;
    const int grp = l >> 4;
    const int n   = l & 15;
    const int ch  = l & 7;
    const int el  = (l >> 3) & 1;

    const float* w1r = w1 + n * 64 + grp * 8;
    bf16x8 aw0, aw1;
    #pragma unroll
    for (int i = 0; i < 8; ++i) {
        aw0[i] = f2bf(w1r[i]);
        aw1[i] = f2bf(w1r[32 + i]);
    }
    const float ca = conv_w[2 * ch];
    const float cc = conv_w[2 * ch + 1];
    const float cb = conv_b[ch];
    float b1r[4], w2r[4];
    #pragma unroll
    for (int r = 0; r < 4; ++r) { b1r[r] = b1[grp * 4 + r]; w2r[r] = w2[grp * 4 + r]; }
    const float w3v = w3[ch];
    const float b2v = b2[0];
    const float b3v = b3[0];

    const int ebase = (blockIdx.x * 4 + wid) * 16;
    const int ce    = min(ebase + n, nEdges - 1);
    const int vs    = edge_index[ce];
    const int vd    = edge_index[nEdges + ce];

#define LOAD_TILE4(T, X1, X2) do { \
    const int sn_ = __shfl(vs, 2 * (T) + el); \
    const int dn_ = __shfl(vd, 2 * (T) + el); \
    const float* p1_ = features + (size_t)sn_ * 64 + grp * 8; \
    const float* p2_ = features + (size_t)dn_ * 64 + grp * 8; \
    X1[0] = *(const f32x4*)(p1_);      X1[1] = *(const f32x4*)(p1_ + 4); \
    X1[2] = *(const f32x4*)(p1_ + 32); X1[3] = *(const f32x4*)(p1_ + 36); \
    X2[0] = *(const f32x4*)(p2_);      X2[1] = *(const f32x4*)(p2_ + 4); \
    X2[2] = *(const f32x4*)(p2_ + 32); X2[3] = *(const f32x4*)(p2_ + 36); \
} while (0)

    f32x4 x1v[4], x2v[4];
    LOAD_TILE4(0, x1v, x2v);
    const f32x2 vca = {ca, ca}, vcc = {cc, cc}, vcb = {cb, cb};
    const f32x2 vz  = {0.f, 0.f};

    #pragma unroll
    for (int t = 0; t < 8; ++t) {
        f32x4 n1v[4], n2v[4];
        if (t < 7) LOAD_TILE4(t + 1, n1v, n2v);
        bf16x8 cf0, cf1;
        #pragma unroll
        for (int p = 0; p < 8; ++p) {
            const int q = p >> 1;
            const int o = (p & 1) * 2;
            f32x2 u = {x1v[q][o], x1v[q][o + 1]};
            f32x2 v = {x2v[q][o], x2v[q][o + 1]};
            f32x2 tt = __builtin_elementwise_fma(vca, u,
                        __builtin_elementwise_fma(vcc, v, vcb));
            tt = __builtin_elementwise_max(tt, vz);
            const short s0 = f2bf(tt[0]), s1 = f2bf(tt[1]);
            if (p < 4) { cf0[2 * (p & 3)] = s0; cf0[2 * (p & 3) + 1] = s1; }
            else       { cf1[2 * (p & 3)] = s0; cf1[2 * (p & 3) + 1] = s1; }
        }
        f32x4 acc = {0.f, 0.f, 0.f, 0.f};
        acc = __builtin_amdgcn_mfma_f32_16x16x32_bf16(aw0, cf0, acc, 0, 0, 0);
        acc = __builtin_amdgcn_mfma_f32_16x16x32_bf16(aw1, cf1, acc, 0, 0, 0);
        float zp = 0.f;
        #pragma unroll
        for (int r = 0; r < 4; ++r) {
            const float h1 = fmaxf(acc[r] + b1r[r], 0.f);
            zp = fmaf(h1, w2r[r], zp);
        }
        zp += __shfl_xor(zp, 16);
        zp += __shfl_xor(zp, 32);
        const float h2 = fmaxf(zp + b2v, 0.f);
        float t3 = h2 * w3v;
        t3 += __shfl_xor(t3, 1);
        t3 += __shfl_xor(t3, 2);
        t3 += __shfl_xor(t3, 4);
        const float z  = t3 + b3v;
        const float sg = 1.0f / (1.0f + __expf(-z));
        if ((l & 55) == 0) {
            const int e = ebase + 2 * t + (l >> 3);
            if (e < nEdges) out[e] = sg;
        }
        if (t < 7) {
            #pragma unroll
            for (int i = 0; i < 4; ++i) { x1v[i] = n1v[i]; x2v[i] = n2v[i]; }
        }
    }
#undef LOAD_TILE4
}

extern "C" void kernel_launch(void* const* d_in, const int* in_sizes, int n_in,
                              void* d_out, int out_size, void* d_ws, size_t ws_size,
                              hipStream_t stream) {
    // 0:x 1:features 2:edge_index 3:conv_w 4:conv_b 5:w1 6:b1 7:w2 8:b2 9:w3 10:b3
    const float* features = (const float*)d_in[1];
    const int*   edge_idx = (const int*)d_in[2];
    const float* conv_w   = (const float*)d_in[3];
    const float* conv_b   = (const float*)d_in[4];
    const float* w1       = (const float*)d_in[5];
    const float* b1       = (const float*)d_in[6];
    const float* w2       = (const float*)d_in[7];
    const float* b2       = (const float*)d_in[8];
    const float* w3       = (const float*)d_in[9];
    const float* b3       = (const float*)d_in[10];
    float*       out      = (float*)d_out;

    const int nEdges = in_sizes[2] / 2;          // (2, E)
    const int nFeat  = in_sizes[1];              // 50000*64

    const size_t need = (size_t)nFeat * sizeof(_Float16);
    if (ws_size >= need) {
        _Float16* feat16 = (_Float16*)d_ws;
        feat_to_f16<<<2048, 256, 0, stream>>>(features, feat16, nFeat / 4);
        // exact-fill persistent launch: 6 blocks/CU x 256 CU = 1536 blocks
        // (VGPR pinned <=85 by __launch_bounds__(256,6) -> 6 waves/SIMD)
        const int nGroups = (nEdges + 15) >> 4;
        const int blocks  = min(1536, (nGroups + 3) / 4);
        edgeconv_f16_xf<<<blocks, 256, 0, stream>>>(feat16, edge_idx,
                                                    conv_w, conv_b, w1, b1, w2, b2, w3, b3,
                                                    out, nEdges);
    } else {
        const dim3 grid((nEdges + 63) / 64);
        edgeconv_mfma2<<<grid, 256, 0, stream>>>(features, edge_idx,
                                                 conv_w, conv_b, w1, b1, w2, b2, w3, b3,
                                                 out, nEdges);
    }
}

// Round 10
// 83.069 us; speedup vs baseline: 4.0337x; 4.0337x over previous
//
#include <hip/hip_runtime.h>
#include <hip/hip_bf16.h>

// ---------------------------------------------------------------------------
// EdgeConvNet — Round 10: lean 64-VGPR persistent kernel (8 waves/SIMD).
//
// R9 lesson: forcing a VGPR cap below the kernel's structural need spills
// catastrophically (FETCH 811MB). R10 shrinks the STRUCTURE to fit the
// 64-reg / 8-waves-per-SIMD occupancy bucket (m69: slots step at 64/128/256):
//   - single feature buffer, load-use per tile (no explicit prefetch);
//     latency hidden by 8-wave TLP instead of ILP registers
//   - no next-group index preload (once-per-group latency, TLP-hidden)
//   - __launch_bounds__(256,8): satisfiable cap + pressure-aware scheduler
//   - grid = 2048 = 8 blocks/CU x 256 CU exact fill
// Proven parts kept: f16 pre-pass, packed v_pk_fma_f16 conv, swapped-operand
// mfma_f32_16x16x32_f16, batched zp[8] epilogue.
// ---------------------------------------------------------------------------

typedef _Float16 f16x8 __attribute__((ext_vector_type(8)));
typedef _Float16 f16x4 __attribute__((ext_vector_type(4)));
typedef _Float16 f16x2 __attribute__((ext_vector_type(2)));
typedef short    bf16x8 __attribute__((ext_vector_type(8)));
typedef float    f32x4  __attribute__((ext_vector_type(4)));
typedef float    f32x2  __attribute__((ext_vector_type(2)));

union U8 { f16x8 v; f16x2 p[4]; };

static __device__ __forceinline__ short f2bf(float f) {
    union { __hip_bfloat16 h; short s; } u;
    u.h = __float2bfloat16(f);
    return u.s;
}

// ---------------------------- pre-pass ------------------------------------
__global__ __launch_bounds__(256) void feat_to_f16(const float* __restrict__ in,
                                                   _Float16* __restrict__ out,
                                                   int n4) {
    int i = blockIdx.x * blockDim.x + threadIdx.x;
    const int stride = gridDim.x * blockDim.x;
    for (; i < n4; i += stride) {
        const f32x4 v = ((const f32x4*)in)[i];
        ((f16x4*)out)[i] = __builtin_convertvector(v, f16x4);
    }
}

// ---------------- main (persistent, lean, 8 waves/SIMD) --------------------
__global__ __launch_bounds__(256, 8) void edgeconv_f16_lean(
    const _Float16* __restrict__ feat16,     // (50000, 64) f16 (in d_ws)
    const int*      __restrict__ edge_index, // (2, E) int32
    const float* __restrict__ conv_w, const float* __restrict__ conv_b,
    const float* __restrict__ w1,     const float* __restrict__ b1,
    const float* __restrict__ w2,     const float* __restrict__ b2,
    const float* __restrict__ w3,     const float* __restrict__ b3,
    float* __restrict__ out, int nEdges)
{
    const int tid = threadIdx.x;
    const int l   = tid & 63;
    const int wid = tid >> 6;
    const int grp = l >> 4;        // k-slice group 0..3
    const int n   = l & 15;        // A row = g ; B col = edge·ch
    const int ch  = l & 7;
    const int el  = (l >> 3) & 1;

    // A fragments: w1[g=n][f], f = grp*8+i (+32 for 2nd MFMA), in f16
    const float* w1r = w1 + n * 64 + grp * 8;
    f16x8 aw0, aw1;
    #pragma unroll
    for (int i = 0; i < 8; ++i) {
        aw0[i] = (_Float16)w1r[i];
        aw1[i] = (_Float16)w1r[32 + i];
    }

    // conv params as packed-f16 splats
    const _Float16 cah = (_Float16)conv_w[2 * ch];
    const _Float16 cch = (_Float16)conv_w[2 * ch + 1];
    const _Float16 cbh = (_Float16)conv_b[ch];
    const f16x2 vca = {cah, cah}, vcc = {cch, cch}, vcb = {cbh, cbh};
    const f16x2 vzero = {(_Float16)0.f, (_Float16)0.f};

    float b1r[4], w2r[4];
    #pragma unroll
    for (int r = 0; r < 4; ++r) {
        b1r[r] = b1[grp * 4 + r];
        w2r[r] = w2[grp * 4 + r];
    }
    const float w3v = w3[ch];
    const float b2v = b2[0];
    const float b3v = b3[0];

    const int nGroups    = (nEdges + 15) >> 4;   // 16-edge groups (8 tiles)
    const int totalWaves = gridDim.x * 4;
    int g = blockIdx.x * 4 + wid;
    if (g >= nGroups) return;

    // this group's 16 edge endpoints, one per lane (lanes 16.. duplicate)
    int ce = min(g * 16 + n, nEdges - 1);
    int vs = edge_index[ce];
    int vd = edge_index[nEdges + ce];

    while (true) {
        // ---------------- phase 1: load -> conv -> MFMA -> fc2 partial ------
        float zp[8];
        #pragma unroll
        for (int t = 0; t < 8; ++t) {
            // tile t: endpoints of edges 2t, 2t+1 (this lane handles edge el)
            const int sn_ = __shfl(vs, 2 * t + el);
            const int dn_ = __shfl(vd, 2 * t + el);
            const _Float16* ps_ = feat16 + (size_t)sn_ * 64 + grp * 8;
            const _Float16* pd_ = feat16 + (size_t)dn_ * 64 + grp * 8;
            U8 s0_, s1_, d0_, d1_;
            s0_.v = *(const f16x8*)(ps_);
            s1_.v = *(const f16x8*)(ps_ + 32);
            d0_.v = *(const f16x8*)(pd_);
            d1_.v = *(const f16x8*)(pd_ + 32);

            // conv + relu in packed f16 -> B fragments
            U8 c0, c1;
            #pragma unroll
            for (int p = 0; p < 4; ++p) {
                f16x2 tL = __builtin_elementwise_fma(vca, s0_.p[p],
                            __builtin_elementwise_fma(vcc, d0_.p[p], vcb));
                c0.p[p] = __builtin_elementwise_max(tL, vzero);
                f16x2 tH = __builtin_elementwise_fma(vca, s1_.p[p],
                            __builtin_elementwise_fma(vcc, d1_.p[p], vcb));
                c1.p[p] = __builtin_elementwise_max(tH, vzero);
            }

            // fc1 via MFMA: C[g][n], fp32 accum
            f32x4 acc = {0.f, 0.f, 0.f, 0.f};
            acc = __builtin_amdgcn_mfma_f32_16x16x32_f16(aw0, c0.v, acc, 0, 0, 0);
            acc = __builtin_amdgcn_mfma_f32_16x16x32_f16(aw1, c1.v, acc, 0, 0, 0);

            // fc2 in-lane partial over this grp's 4 g-rows
            float z_ = 0.f;
            #pragma unroll
            for (int r = 0; r < 4; ++r) {
                const float h1 = fmaxf(acc[r] + b1r[r], 0.f);
                z_ = fmaf(h1, w2r[r], z_);
            }
            zp[t] = z_;
        }

        // ---------------- phase 2: batched shuffle reduces ------------------
        #pragma unroll
        for (int t = 0; t < 8; ++t) zp[t] += __shfl_xor(zp[t], 16);
        #pragma unroll
        for (int t = 0; t < 8; ++t) zp[t] += __shfl_xor(zp[t], 32);
        #pragma unroll
        for (int t = 0; t < 8; ++t) {
            const float h2 = fmaxf(zp[t] + b2v, 0.f);
            zp[t] = h2 * w3v;
        }
        #pragma unroll
        for (int t = 0; t < 8; ++t) zp[t] += __shfl_xor(zp[t], 1);
        #pragma unroll
        for (int t = 0; t < 8; ++t) zp[t] += __shfl_xor(zp[t], 2);
        #pragma unroll
        for (int t = 0; t < 8; ++t) zp[t] += __shfl_xor(zp[t], 4);
        #pragma unroll
        for (int t = 0; t < 8; ++t) {
            const float z  = zp[t] + b3v;
            const float sg = 1.0f / (1.0f + __expf(-z));
            if ((l & 55) == 0) {                  // lanes 0 (el=0), 8 (el=1)
                const int e = g * 16 + 2 * t + (l >> 3);
                if (e < nEdges) out[e] = sg;
            }
        }

        // ---------------- next group -----------------------------------------
        g += totalWaves;
        if (g >= nGroups) break;
        ce = min(g * 16 + n, nEdges - 1);
        vs = edge_index[ce];
        vd = edge_index[nEdges + ce];
    }
}

// ------------------- fallback: round-4 bf16 kernel (proven) ----------------
__global__ __launch_bounds__(256) void edgeconv_mfma2(
    const float* __restrict__ features, const int* __restrict__ edge_index,
    const float* __restrict__ conv_w, const float* __restrict__ conv_b,
    const float* __restrict__ w1, const float* __restrict__ b1,
    const float* __restrict__ w2, const float* __restrict__ b2,
    const float* __restrict__ w3, const float* __restrict__ b3,
    float* __restrict__ out, int nEdges)
{
    const int tid = threadIdx.x;
    const int l   = tid & 63;
    const int wid = tid >> 6;
    const int grp = l >> 4;
    const int n   = l & 15;
    const int ch  = l & 7;
    const int el  = (l >> 3) & 1;

    const float* w1r = w1 + n * 64 + grp * 8;
    bf16x8 aw0, aw1;
    #pragma unroll
    for (int i = 0; i < 8; ++i) {
        aw0[i] = f2bf(w1r[i]);
        aw1[i] = f2bf(w1r[32 + i]);
    }
    const float ca = conv_w[2 * ch];
    const float cc = conv_w[2 * ch + 1];
    const float cb = conv_b[ch];
    float b1r[4], w2r[4];
    #pragma unroll
    for (int r = 0; r < 4; ++r) { b1r[r] = b1[grp * 4 + r]; w2r[r] = w2[grp * 4 + r]; }
    const float w3v = w3[ch];
    const float b2v = b2[0];
    const float b3v = b3[0];

    const int ebase = (blockIdx.x * 4 + wid) * 16;
    const int ce    = min(ebase + n, nEdges - 1);
    const int vs    = edge_index[ce];
    const int vd    = edge_index[nEdges + ce];

#define LOAD_TILE4(T, X1, X2) do { \
    const int sn_ = __shfl(vs, 2 * (T) + el); \
    const int dn_ = __shfl(vd, 2 * (T) + el); \
    const float* p1_ = features + (size_t)sn_ * 64 + grp * 8; \
    const float* p2_ = features + (size_t)dn_ * 64 + grp * 8; \
    X1[0] = *(const f32x4*)(p1_);      X1[1] = *(const f32x4*)(p1_ + 4); \
    X1[2] = *(const f32x4*)(p1_ + 32); X1[3] = *(const f32x4*)(p1_ + 36); \
    X2[0] = *(const f32x4*)(p2_);      X2[1] = *(const f32x4*)(p2_ + 4); \
    X2[2] = *(const f32x4*)(p2_ + 32); X2[3] = *(const f32x4*)(p2_ + 36); \
} while (0)

    f32x4 x1v[4], x2v[4];
    LOAD_TILE4(0, x1v, x2v);
    const f32x2 vca = {ca, ca}, vcc = {cc, cc}, vcb = {cb, cb};
    const f32x2 vz  = {0.f, 0.f};

    #pragma unroll
    for (int t = 0; t < 8; ++t) {
        f32x4 n1v[4], n2v[4];
        if (t < 7) LOAD_TILE4(t + 1, n1v, n2v);
        bf16x8 cf0, cf1;
        #pragma unroll
        for (int p = 0; p < 8; ++p) {
            const int q = p >> 1;
            const int o = (p & 1) * 2;
            f32x2 u = {x1v[q][o], x1v[q][o + 1]};
            f32x2 v = {x2v[q][o], x2v[q][o + 1]};
            f32x2 tt = __builtin_elementwise_fma(vca, u,
                        __builtin_elementwise_fma(vcc, v, vcb));
            tt = __builtin_elementwise_max(tt, vz);
            const short s0 = f2bf(tt[0]), s1 = f2bf(tt[1]);
            if (p < 4) { cf0[2 * (p & 3)] = s0; cf0[2 * (p & 3) + 1] = s1; }
            else       { cf1[2 * (p & 3)] = s0; cf1[2 * (p & 3) + 1] = s1; }
        }
        f32x4 acc = {0.f, 0.f, 0.f, 0.f};
        acc = __builtin_amdgcn_mfma_f32_16x16x32_bf16(aw0, cf0, acc, 0, 0, 0);
        acc = __builtin_amdgcn_mfma_f32_16x16x32_bf16(aw1, cf1, acc, 0, 0, 0);
        float zp = 0.f;
        #pragma unroll
        for (int r = 0; r < 4; ++r) {
            const float h1 = fmaxf(acc[r] + b1r[r], 0.f);
            zp = fmaf(h1, w2r[r], zp);
        }
        zp += __shfl_xor(zp, 16);
        zp += __shfl_xor(zp, 32);
        const float h2 = fmaxf(zp + b2v, 0.f);
        float t3 = h2 * w3v;
        t3 += __shfl_xor(t3, 1);
        t3 += __shfl_xor(t3, 2);
        t3 += __shfl_xor(t3, 4);
        const float z  = t3 + b3v;
        const float sg = 1.0f / (1.0f + __expf(-z));
        if ((l & 55) == 0) {
            const int e = ebase + 2 * t + (l >> 3);
            if (e < nEdges) out[e] = sg;
        }
        if (t < 7) {
            #pragma unroll
            for (int i = 0; i < 4; ++i) { x1v[i] = n1v[i]; x2v[i] = n2v[i]; }
        }
    }
#undef LOAD_TILE4
}

extern "C" void kernel_launch(void* const* d_in, const int* in_sizes, int n_in,
                              void* d_out, int out_size, void* d_ws, size_t ws_size,
                              hipStream_t stream) {
    // 0:x 1:features 2:edge_index 3:conv_w 4:conv_b 5:w1 6:b1 7:w2 8:b2 9:w3 10:b3
    const float* features = (const float*)d_in[1];
    const int*   edge_idx = (const int*)d_in[2];
    const float* conv_w   = (const float*)d_in[3];
    const float* conv_b   = (const float*)d_in[4];
    const float* w1       = (const float*)d_in[5];
    const float* b1       = (const float*)d_in[6];
    const float* w2       = (const float*)d_in[7];
    const float* b2       = (const float*)d_in[8];
    const float* w3       = (const float*)d_in[9];
    const float* b3       = (const float*)d_in[10];
    float*       out      = (float*)d_out;

    const int nEdges = in_sizes[2] / 2;          // (2, E)
    const int nFeat  = in_sizes[1];              // 50000*64

    const size_t need = (size_t)nFeat * sizeof(_Float16);
    if (ws_size >= need) {
        _Float16* feat16 = (_Float16*)d_ws;
        feat_to_f16<<<2048, 256, 0, stream>>>(features, feat16, nFeat / 4);
        // exact-fill persistent launch: 8 blocks/CU x 256 CU = 2048 blocks
        // (64-VGPR bucket -> 8 waves/SIMD, m69 occupancy quantum)
        const int nGroups = (nEdges + 15) >> 4;
        const int blocks  = min(2048, (nGroups + 3) / 4);
        edgeconv_f16_lean<<<blocks, 256, 0, stream>>>(feat16, edge_idx,
                                                      conv_w, conv_b, w1, b1, w2, b2, w3, b3,
                                                      out, nEdges);
    } else {
        const dim3 grid((nEdges + 63) / 64);
        edgeconv_mfma2<<<grid, 256, 0, stream>>>(features, edge_idx,
                                                 conv_w, conv_b, w1, b1, w2, b2, w3, b3,
                                                 out, nEdges);
    }
}

// Round 11
// 82.191 us; speedup vs baseline: 4.0768x; 1.0107x over previous
//
#include <hip/hip_runtime.h>
#include <hip/hip_bf16.h>

// ---------------------------------------------------------------------------
// EdgeConvNet — Round 11: spill-free lean kernel (8 waves/SIMD, zp[4] halves).
//
// R10 counters: (256,8) cap nearly met but a few regs spilled (~40MB scratch
// round-trip, occupancy capped at 65%). R11 shaves live state to fit 64:
//   - 16-edge group processed as TWO 4-tile half-phases (zp[4] not zp[8])
//   - fc1 bias folded into the MFMA accumulator INIT (C-in is free)
//   - trimmed clamps/admin; inline zero for pk_max
// Everything else proven & kept: f16 pre-pass, packed v_pk_fma_f16 conv,
// swapped-operand mfma_f32_16x16x32_f16, batched epilogue, persistent
// exact-fill 2048-block launch.
// ---------------------------------------------------------------------------

typedef _Float16 f16x8 __attribute__((ext_vector_type(8)));
typedef _Float16 f16x4 __attribute__((ext_vector_type(4)));
typedef _Float16 f16x2 __attribute__((ext_vector_type(2)));
typedef short    bf16x8 __attribute__((ext_vector_type(8)));
typedef float    f32x4  __attribute__((ext_vector_type(4)));
typedef float    f32x2  __attribute__((ext_vector_type(2)));

union U8 { f16x8 v; f16x2 p[4]; };

static __device__ __forceinline__ short f2bf(float f) {
    union { __hip_bfloat16 h; short s; } u;
    u.h = __float2bfloat16(f);
    return u.s;
}

// ---------------------------- pre-pass ------------------------------------
__global__ __launch_bounds__(256) void feat_to_f16(const float* __restrict__ in,
                                                   _Float16* __restrict__ out,
                                                   int n4) {
    int i = blockIdx.x * blockDim.x + threadIdx.x;
    const int stride = gridDim.x * blockDim.x;
    for (; i < n4; i += stride) {
        const f32x4 v = ((const f32x4*)in)[i];
        ((f16x4*)out)[i] = __builtin_convertvector(v, f16x4);
    }
}

// ------------- main (persistent, spill-free lean, 8 waves/SIMD) ------------
__global__ __launch_bounds__(256, 8) void edgeconv_f16_l2(
    const _Float16* __restrict__ feat16,     // (50000, 64) f16 (in d_ws)
    const int*      __restrict__ edge_index, // (2, E) int32
    const float* __restrict__ conv_w, const float* __restrict__ conv_b,
    const float* __restrict__ w1,     const float* __restrict__ b1,
    const float* __restrict__ w2,     const float* __restrict__ b2,
    const float* __restrict__ w3,     const float* __restrict__ b3,
    float* __restrict__ out, int nEdges)
{
    const int tid = threadIdx.x;
    const int l   = tid & 63;
    const int wid = tid >> 6;
    const int grp = l >> 4;        // k-slice group 0..3
    const int n   = l & 15;        // A row = g ; B col = edge·ch
    const int ch  = l & 7;
    const int el  = (l >> 3) & 1;

    // A fragments: w1[g=n][f], f = grp*8+i (+32 for 2nd MFMA), in f16
    const float* w1r = w1 + n * 64 + grp * 8;
    f16x8 aw0, aw1;
    #pragma unroll
    for (int i = 0; i < 8; ++i) {
        aw0[i] = (_Float16)w1r[i];
        aw1[i] = (_Float16)w1r[32 + i];
    }

    // conv params as packed-f16 splats
    const _Float16 cah = (_Float16)conv_w[2 * ch];
    const _Float16 cch = (_Float16)conv_w[2 * ch + 1];
    const _Float16 cbh = (_Float16)conv_b[ch];
    const f16x2 vca = {cah, cah}, vcc = {cch, cch}, vcb = {cbh, cbh};
    const f16x2 vzero = {(_Float16)0.f, (_Float16)0.f};

    // fc1 bias folded into accumulator init (MFMA C-in is free)
    f32x4 accInit;
    float w2r[4];
    #pragma unroll
    for (int r = 0; r < 4; ++r) {
        accInit[r] = b1[grp * 4 + r];
        w2r[r]     = w2[grp * 4 + r];
    }
    const float w3v = w3[ch];
    const float b2v = b2[0];
    const float b3v = b3[0];

    const int nGroups    = (nEdges + 15) >> 4;   // 16-edge groups
    const int totalWaves = gridDim.x * 4;
    int g = blockIdx.x * 4 + wid;
    if (g >= nGroups) return;

    // this group's 16 edge endpoints, one per lane (lanes 16.. duplicate)
    int ce = min(g * 16 + n, nEdges - 1);
    int vs = edge_index[ce];
    int vd = edge_index[nEdges + ce];

    while (true) {
        // two half-phases of 4 tiles each (zp[4] live at a time)
        #pragma unroll
        for (int half = 0; half < 2; ++half) {
            float zp[4];
            #pragma unroll
            for (int tt = 0; tt < 4; ++tt) {
                const int t = half * 4 + tt;
                // tile t: endpoints of edges 2t, 2t+1 (this lane: edge el)
                const int sn_ = __shfl(vs, 2 * t + el);
                const int dn_ = __shfl(vd, 2 * t + el);
                const _Float16* ps_ = feat16 + (size_t)sn_ * 64 + grp * 8;
                const _Float16* pd_ = feat16 + (size_t)dn_ * 64 + grp * 8;
                U8 s0_, s1_, d0_, d1_;
                s0_.v = *(const f16x8*)(ps_);
                s1_.v = *(const f16x8*)(ps_ + 32);
                d0_.v = *(const f16x8*)(pd_);
                d1_.v = *(const f16x8*)(pd_ + 32);

                // conv + relu in packed f16 -> B fragments
                U8 c0, c1;
                #pragma unroll
                for (int p = 0; p < 4; ++p) {
                    f16x2 tL = __builtin_elementwise_fma(vca, s0_.p[p],
                                __builtin_elementwise_fma(vcc, d0_.p[p], vcb));
                    c0.p[p] = __builtin_elementwise_max(tL, vzero);
                    f16x2 tH = __builtin_elementwise_fma(vca, s1_.p[p],
                                __builtin_elementwise_fma(vcc, d1_.p[p], vcb));
                    c1.p[p] = __builtin_elementwise_max(tH, vzero);
                }

                // fc1 via MFMA: C[g][n], acc pre-loaded with b1
                f32x4 acc = accInit;
                acc = __builtin_amdgcn_mfma_f32_16x16x32_f16(aw0, c0.v, acc, 0, 0, 0);
                acc = __builtin_amdgcn_mfma_f32_16x16x32_f16(aw1, c1.v, acc, 0, 0, 0);

                // fc2 in-lane partial over this grp's 4 g-rows
                float z_ = 0.f;
                #pragma unroll
                for (int r = 0; r < 4; ++r) {
                    const float h1 = fmaxf(acc[r], 0.f);   // bias already in
                    z_ = fmaf(h1, w2r[r], z_);
                }
                zp[tt] = z_;
            }

            // batched shuffle reduces over the 4 tiles of this half
            #pragma unroll
            for (int tt = 0; tt < 4; ++tt) zp[tt] += __shfl_xor(zp[tt], 16);
            #pragma unroll
            for (int tt = 0; tt < 4; ++tt) zp[tt] += __shfl_xor(zp[tt], 32);
            #pragma unroll
            for (int tt = 0; tt < 4; ++tt) {
                const float h2 = fmaxf(zp[tt] + b2v, 0.f);
                zp[tt] = h2 * w3v;
            }
            #pragma unroll
            for (int tt = 0; tt < 4; ++tt) zp[tt] += __shfl_xor(zp[tt], 1);
            #pragma unroll
            for (int tt = 0; tt < 4; ++tt) zp[tt] += __shfl_xor(zp[tt], 2);
            #pragma unroll
            for (int tt = 0; tt < 4; ++tt) zp[tt] += __shfl_xor(zp[tt], 4);
            #pragma unroll
            for (int tt = 0; tt < 4; ++tt) {
                const float z  = zp[tt] + b3v;
                const float sg = 1.0f / (1.0f + __expf(-z));
                if ((l & 55) == 0) {              // lanes 0 (el=0), 8 (el=1)
                    const int e = g * 16 + half * 8 + 2 * tt + (l >> 3);
                    if (e < nEdges) out[e] = sg;
                }
            }
        }

        // next group
        g += totalWaves;
        if (g >= nGroups) break;
        ce = min(g * 16 + n, nEdges - 1);
        vs = edge_index[ce];
        vd = edge_index[nEdges + ce];
    }
}

// ------------------- fallback: round-4 bf16 kernel (proven) ----------------
__global__ __launch_bounds__(256) void edgeconv_mfma2(
    const float* __restrict__ features, const int* __restrict__ edge_index,
    const float* __restrict__ conv_w, const float* __restrict__ conv_b,
    const float* __restrict__ w1, const float* __restrict__ b1,
    const float* __restrict__ w2, const float* __restrict__ b2,
    const float* __restrict__ w3, const float* __restrict__ b3,
    float* __restrict__ out, int nEdges)
{
    const int tid = threadIdx.x;
    const int l   = tid & 63;
    const int wid = tid >> 6;
    const int grp = l >> 4;
    const int n   = l & 15;
    const int ch  = l & 7;
    const int el  = (l >> 3) & 1;

    const float* w1r = w1 + n * 64 + grp * 8;
    bf16x8 aw0, aw1;
    #pragma unroll
    for (int i = 0; i < 8; ++i) {
        aw0[i] = f2bf(w1r[i]);
        aw1[i] = f2bf(w1r[32 + i]);
    }
    const float ca = conv_w[2 * ch];
    const float cc = conv_w[2 * ch + 1];
    const float cb = conv_b[ch];
    float b1r[4], w2r[4];
    #pragma unroll
    for (int r = 0; r < 4; ++r) { b1r[r] = b1[grp * 4 + r]; w2r[r] = w2[grp * 4 + r]; }
    const float w3v = w3[ch];
    const float b2v = b2[0];
    const float b3v = b3[0];

    const int ebase = (blockIdx.x * 4 + wid) * 16;
    const int ce    = min(ebase + n, nEdges - 1);
    const int vs    = edge_index[ce];
    const int vd    = edge_index[nEdges + ce];

#define LOAD_TILE4(T, X1, X2) do { \
    const int sn_ = __shfl(vs, 2 * (T) + el); \
    const int dn_ = __shfl(vd, 2 * (T) + el); \
    const float* p1_ = features + (size_t)sn_ * 64 + grp * 8; \
    const float* p2_ = features + (size_t)dn_ * 64 + grp * 8; \
    X1[0] = *(const f32x4*)(p1_);      X1[1] = *(const f32x4*)(p1_ + 4); \
    X1[2] = *(const f32x4*)(p1_ + 32); X1[3] = *(const f32x4*)(p1_ + 36); \
    X2[0] = *(const f32x4*)(p2_);      X2[1] = *(const f32x4*)(p2_ + 4); \
    X2[2] = *(const f32x4*)(p2_ + 32); X2[3] = *(const f32x4*)(p2_ + 36); \
} while (0)

    f32x4 x1v[4], x2v[4];
    LOAD_TILE4(0, x1v, x2v);
    const f32x2 vca = {ca, ca}, vcc = {cc, cc}, vcb = {cb, cb};
    const f32x2 vz  = {0.f, 0.f};

    #pragma unroll
    for (int t = 0; t < 8; ++t) {
        f32x4 n1v[4], n2v[4];
        if (t < 7) LOAD_TILE4(t + 1, n1v, n2v);
        bf16x8 cf0, cf1;
        #pragma unroll
        for (int p = 0; p < 8; ++p) {
            const int q = p >> 1;
            const int o = (p & 1) * 2;
            f32x2 u = {x1v[q][o], x1v[q][o + 1]};
            f32x2 v = {x2v[q][o], x2v[q][o + 1]};
            f32x2 tt = __builtin_elementwise_fma(vca, u,
                        __builtin_elementwise_fma(vcc, v, vcb));
            tt = __builtin_elementwise_max(tt, vz);
            const short s0 = f2bf(tt[0]), s1 = f2bf(tt[1]);
            if (p < 4) { cf0[2 * (p & 3)] = s0; cf0[2 * (p & 3) + 1] = s1; }
            else       { cf1[2 * (p & 3)] = s0; cf1[2 * (p & 3) + 1] = s1; }
        }
        f32x4 acc = {0.f, 0.f, 0.f, 0.f};
        acc = __builtin_amdgcn_mfma_f32_16x16x32_bf16(aw0, cf0, acc, 0, 0, 0);
        acc = __builtin_amdgcn_mfma_f32_16x16x32_bf16(aw1, cf1, acc, 0, 0, 0);
        float zp = 0.f;
        #pragma unroll
        for (int r = 0; r < 4; ++r) {
            const float h1 = fmaxf(acc[r] + b1r[r], 0.f);
            zp = fmaf(h1, w2r[r], zp);
        }
        zp += __shfl_xor(zp, 16);
        zp += __shfl_xor(zp, 32);
        const float h2 = fmaxf(zp + b2v, 0.f);
        float t3 = h2 * w3v;
        t3 += __shfl_xor(t3, 1);
        t3 += __shfl_xor(t3, 2);
        t3 += __shfl_xor(t3, 4);
        const float z  = t3 + b3v;
        const float sg = 1.0f / (1.0f + __expf(-z));
        if ((l & 55) == 0) {
            const int e = ebase + 2 * t + (l >> 3);
            if (e < nEdges) out[e] = sg;
        }
        if (t < 7) {
            #pragma unroll
            for (int i = 0; i < 4; ++i) { x1v[i] = n1v[i]; x2v[i] = n2v[i]; }
        }
    }
#undef LOAD_TILE4
}

extern "C" void kernel_launch(void* const* d_in, const int* in_sizes, int n_in,
                              void* d_out, int out_size, void* d_ws, size_t ws_size,
                              hipStream_t stream) {
    // 0:x 1:features 2:edge_index 3:conv_w 4:conv_b 5:w1 6:b1 7:w2 8:b2 9:w3 10:b3
    const float* features = (const float*)d_in[1];
    const int*   edge_idx = (const int*)d_in[2];
    const float* conv_w   = (const float*)d_in[3];
    const float* conv_b   = (const float*)d_in[4];
    const float* w1       = (const float*)d_in[5];
    const float* b1       = (const float*)d_in[6];
    const float* w2       = (const float*)d_in[7];
    const float* b2       = (const float*)d_in[8];
    const float* w3       = (const float*)d_in[9];
    const float* b3       = (const float*)d_in[10];
    float*       out      = (float*)d_out;

    const int nEdges = in_sizes[2] / 2;          // (2, E)
    const int nFeat  = in_sizes[1];              // 50000*64

    const size_t need = (size_t)nFeat * sizeof(_Float16);
    if (ws_size >= need) {
        _Float16* feat16 = (_Float16*)d_ws;
        feat_to_f16<<<2048, 256, 0, stream>>>(features, feat16, nFeat / 4);
        // exact-fill persistent launch: 8 blocks/CU x 256 CU = 2048 blocks
        const int nGroups = (nEdges + 15) >> 4;
        const int blocks  = min(2048, (nGroups + 3) / 4);
        edgeconv_f16_l2<<<blocks, 256, 0, stream>>>(feat16, edge_idx,
                                                    conv_w, conv_b, w1, b1, w2, b2, w3, b3,
                                                    out, nEdges);
    } else {
        const dim3 grid((nEdges + 63) / 64);
        edgeconv_mfma2<<<grid, 256, 0, stream>>>(features, edge_idx,
                                                 conv_w, conv_b, w1, b1, w2, b2, w3, b3,
                                                 out, nEdges);
    }
}